// Round 3
// baseline (369.203 us; speedup 1.0000x reference)
//
#include <hip/hip_runtime.h>

// Problem constants: b=16, c=128, groups=8, h=w=64 -> n=4096
#define NB   16
#define NC   128
#define NPOS 4096

typedef short bf16x8 __attribute__((ext_vector_type(8)));   // 8 bf16 (4 VGPRs)
typedef float f32x4  __attribute__((ext_vector_type(4)));
typedef float f32x16 __attribute__((ext_vector_type(16)));
typedef unsigned int u32x4 __attribute__((ext_vector_type(4)));

// softmax scale folded into q at QKV time: log2(e)/sqrt(128)
#define SCF 0.12751743075095855f

static __device__ __forceinline__ unsigned short f2bf(float f) {
    unsigned int u = __builtin_bit_cast(unsigned int, f);
    u += 0x7FFFu + ((u >> 16) & 1u);   // round-to-nearest-even
    return (unsigned short)(u >> 16);
}

// pack two floats -> bf16x2 dword (truncating; exp2-arg pre-biased to center)
static __device__ __forceinline__ unsigned int pkbf(float hi, float lo) {
    return __builtin_amdgcn_perm(__builtin_bit_cast(unsigned int, hi),
                                 __builtin_bit_cast(unsigned int, lo), 0x07060302u);
}

// ---------------- K0: fp32 -> bf16 weight conversion (64 blocks x 256) ----------------
__global__ void wconv_kernel(const float* __restrict__ wq, const float* __restrict__ wk,
                             const float* __restrict__ wv, const float* __restrict__ wf,
                             unsigned short* __restrict__ oq, unsigned short* __restrict__ ok,
                             unsigned short* __restrict__ ov, unsigned short* __restrict__ of) {
    int i = blockIdx.x * 256 + threadIdx.x;
    oq[i] = f2bf(wq[i]); ok[i] = f2bf(wk[i]); ov[i] = f2bf(wv[i]); of[i] = f2bf(wf[i]);
}

// ---------------- K1: GroupNorm stats, one block per (b,g), 128 blocks ----------------
__global__ void gnstat_kernel(const float* __restrict__ x, float* __restrict__ mean,
                              float* __restrict__ rstd) {
    int bg = blockIdx.x;
    const float* p = x + (size_t)bg * 65536;
    int t = threadIdx.x;
    float s = 0.f, q = 0.f;
    for (int it = 0; it < 64; ++it) {
        f32x4 v = *(const f32x4*)(p + it * 1024 + t * 4);
        s += v[0] + v[1] + v[2] + v[3];
        q += v[0] * v[0] + v[1] * v[1] + v[2] * v[2] + v[3] * v[3];
    }
    for (int m = 1; m < 64; m <<= 1) { s += __shfl_xor(s, m); q += __shfl_xor(q, m); }
    __shared__ float ls[4], lq[4];
    int w = t >> 6;
    if ((t & 63) == 0) { ls[w] = s; lq[w] = q; }
    __syncthreads();
    if (t == 0) {
        s = ls[0] + ls[1] + ls[2] + ls[3];
        q = lq[0] + lq[1] + lq[2] + lq[3];
        float mu  = s * (1.0f / 65536.0f);
        float var = q * (1.0f / 65536.0f) - mu * mu;
        mean[bg] = mu;
        rstd[bg] = rsqrtf(var + 1e-5f);
    }
}

// ---------------- K2: GN-apply + QKV GEMMs (grid 64 x 16, 256 thr) ----------------
// q is pre-scaled by SCF (softmax scale fold).
__global__ __launch_bounds__(256) void qkv_kernel(
    const float* __restrict__ x, const float* __restrict__ gnw, const float* __restrict__ gnb,
    const float* __restrict__ mean, const float* __restrict__ rstd,
    const unsigned short* __restrict__ wqb, const unsigned short* __restrict__ wkb,
    const unsigned short* __restrict__ wvb,
    const float* __restrict__ bq, const float* __restrict__ bk, const float* __restrict__ bv,
    unsigned short* __restrict__ qT, unsigned short* __restrict__ kT, unsigned short* __restrict__ vv) {
    __shared__ __attribute__((aligned(16))) unsigned short xn[64 * 136];  // [i][c], stride 136
    const int b = blockIdx.y, i0 = blockIdx.x * 64;
    const int t = threadIdx.x;
    {
        int iL = (t & 15) * 4;
        int cb = (t >> 4) * 2;
        for (int cg = 0; cg < 4; ++cg) {
            int c = cg * 32 + cb;
            int g = c >> 4;
            float mu = mean[b * 8 + g], rs = rstd[b * 8 + g];
            float ga0 = gnw[c] * rs,     be0 = gnb[c]     - mu * ga0;
            float ga1 = gnw[c + 1] * rs, be1 = gnb[c + 1] - mu * ga1;
            const float* p0 = x + ((size_t)(b * NC + c)) * NPOS + i0 + iL;
            f32x4 v0 = *(const f32x4*)p0;
            f32x4 v1 = *(const f32x4*)(p0 + NPOS);
            for (int e = 0; e < 4; ++e) {
                unsigned int u = (unsigned)f2bf(v0[e] * ga0 + be0) |
                                 ((unsigned)f2bf(v1[e] * ga1 + be1) << 16);
                *(unsigned int*)&xn[(iL + e) * 136 + c] = u;
            }
        }
    }
    __syncthreads();

    const int lane = t & 63, w = t >> 6, quad = lane >> 4, li = lane & 15;

    bf16x8 ax[4];
    for (int kc = 0; kc < 4; ++kc)
        ax[kc] = *(const bf16x8*)&xn[(w * 16 + li) * 136 + kc * 32 + quad * 8];
    for (int wt = 0; wt < 2; ++wt) {
        const unsigned short* W = wt ? wkb : wqb;
        const float* bias = wt ? bk : bq;
        unsigned short* dst = wt ? kT : qT;
        const float osc = wt ? 1.0f : SCF;
        for (int nt = 0; nt < 8; ++nt) {
            f32x4 d = {0.f, 0.f, 0.f, 0.f};
            for (int kc = 0; kc < 4; ++kc) {
                bf16x8 bw = *(const bf16x8*)&W[(nt * 16 + li) * 128 + kc * 32 + quad * 8];
                d = __builtin_amdgcn_mfma_f32_16x16x32_bf16(ax[kc], bw, d, 0, 0, 0);
            }
            float bb = bias[nt * 16 + li];
            size_t base = ((size_t)b * NPOS + i0 + w * 16 + quad * 4) * NC + nt * 16 + li;
            for (int rr = 0; rr < 4; ++rr)
                dst[base + (size_t)rr * NC] = f2bf((d[rr] + bb) * osc);
        }
    }

    bf16x8 av[2][4];
    for (int mt = 0; mt < 2; ++mt)
        for (int kc = 0; kc < 4; ++kc)
            av[mt][kc] = *(const bf16x8*)&wvb[((w * 2 + mt) * 16 + li) * 128 + kc * 32 + quad * 8];
    for (int nt = 0; nt < 4; ++nt) {
        bf16x8 bx[4];
        for (int kc = 0; kc < 4; ++kc)
            bx[kc] = *(const bf16x8*)&xn[(nt * 16 + li) * 136 + kc * 32 + quad * 8];
        for (int mt = 0; mt < 2; ++mt) {
            f32x4 d = {0.f, 0.f, 0.f, 0.f};
            for (int kc = 0; kc < 4; ++kc)
                d = __builtin_amdgcn_mfma_f32_16x16x32_bf16(av[mt][kc], bx[kc], d, 0, 0, 0);
            int o0 = (w * 2 + mt) * 16 + quad * 4;
            for (int rr = 0; rr < 4; ++rr) {
                float val = d[rr] + bv[o0 + rr];
                vv[((size_t)(b * NC + o0 + rr)) * NPOS + i0 + nt * 16 + li] = f2bf(val);
            }
        }
    }
}

// ---------------- K3: flash attention, 32x32x16 MFMA, no P round-trip ----------------
// grid (16 b, 32 i-tiles), 256 thr = 4 waves x 32 q-rows. j-tile = 64.
// S^T = K Q^T (A=K from LDS, B=Q regs): col = i = il -> softmax state per-lane scalar.
// P^T B-frags built in-register via one half-wave shfl_xor(32) per 2 dwords.
// O^T[c][i] = sum_j V^T[c][j] P^T[j][i] (A=V from LDS, B=P regs).
__global__ __launch_bounds__(256, 3) void flash_kernel(
    const unsigned short* __restrict__ qT, const unsigned short* __restrict__ kT,
    const unsigned short* __restrict__ vv, unsigned short* __restrict__ oT) {
    __shared__ __attribute__((aligned(16))) unsigned short kt[64 * 128];   // [j][c] swizzled
    __shared__ __attribute__((aligned(16))) unsigned short vt[128 * 64];   // [c][j] swizzled
    const int b = blockIdx.x, i0 = blockIdx.y * 128;
    const int t = threadIdx.x, lane = t & 63, w = t >> 6;
    const int il = lane & 31, h = lane >> 5;

    // Q B-fragments (q pre-scaled by SCF), resident all 64 iters
    bf16x8 qb[8];
    for (int kc = 0; kc < 8; ++kc)
        qb[kc] = *(const bf16x8*)&qT[((size_t)b * NPOS + i0 + w * 32 + il) * NC + kc * 16 + h * 8];

    float mrow = -1e30f, lrow = 0.f;
    f32x16 acc[4];   // acc[ct]: O^T rows c = 32ct + (r&3)+8(r>>2)+4h, col i = il
    for (int ct = 0; ct < 4; ++ct)
        for (int r = 0; r < 16; ++r) acc[ct][r] = 0.f;

    const int kjj = t >> 2, kq = t & 3;     // K stage: row j, c-chunk
    const int vc  = t >> 1, vq = t & 1;     // V stage: row c, j-chunk
    const unsigned short* ksrc = &kT[((size_t)b * NPOS + kjj) * NC + kq * 32];
    const unsigned short* vsrc = &vv[((size_t)(b * NC + vc)) * NPOS + vq * 32];
    unsigned short* dkb = &kt[kjj * 128];
    unsigned short* dvb = &vt[vc * 64];

    for (int jt = 0; jt < 64; ++jt) {
        __syncthreads();
        #pragma unroll
        for (int m = 0; m < 4; ++m) {
            *(bf16x8*)(dkb + (((kq * 4 + m) ^ (kjj & 7)) << 3)) = *(const bf16x8*)(ksrc + m * 8);
            *(bf16x8*)(dvb + (((vq * 4 + m) ^ (vc  & 7)) << 3)) = *(const bf16x8*)(vsrc + m * 8);
        }
        ksrc += 64 * NC;   // next 64 j-rows
        vsrc += 64;        // next 64 j-cols
        __syncthreads();

        // S^T tiles: st0 = j 0..31, st1 = j 32..63 ; col = i = il
        f32x16 st0, st1;
        for (int r = 0; r < 16; ++r) { st0[r] = 0.f; st1[r] = 0.f; }
        #pragma unroll
        for (int kc = 0; kc < 8; ++kc) {
            bf16x8 a0 = *(const bf16x8*)&kt[il * 128 + (((kc * 2 + h) ^ (il & 7)) << 3)];
            bf16x8 a1 = *(const bf16x8*)&kt[(32 + il) * 128 + (((kc * 2 + h) ^ (il & 7)) << 3)];
            st0 = __builtin_amdgcn_mfma_f32_32x32x16_bf16(a0, qb[kc], st0, 0, 0, 0);
            st1 = __builtin_amdgcn_mfma_f32_32x32x16_bf16(a1, qb[kc], st1, 0, 0, 0);
        }

        // online softmax: per-lane scalar state (this lane's column i = il)
        float mx = st0[0];
        #pragma unroll
        for (int r = 1; r < 16; ++r) mx = fmaxf(mx, st0[r]);
        #pragma unroll
        for (int r = 0; r < 16; ++r) mx = fmaxf(mx, st1[r]);
        mx = fmaxf(mx, __shfl_xor(mx, 32));
        float mn = fmaxf(mrow, mx);
        float alpha = __builtin_amdgcn_exp2f(mrow - mn);
        mrow = mn;
        // mc = mn - log2(1+2^-9): centers pkbf truncation (CP cancels in final ratio)
        float mc = mn - 0.0028150156f;

        float p0[16], p1[16];
        float rs = 0.f;
        #pragma unroll
        for (int r = 0; r < 16; ++r) {
            p0[r] = __builtin_amdgcn_exp2f(st0[r] - mc);
            p1[r] = __builtin_amdgcn_exp2f(st1[r] - mc);
            rs += p0[r] + p1[r];
        }
        rs += __shfl_xor(rs, 32);
        lrow = lrow * alpha + rs;

        // Build P^T B-frags in-register. For k-chunk j16*f..j16*f+15:
        //  h=0 lane: [own(j lo4), own, recv(j mid4), recv] ; h=1: [recv, recv, own(j hi4), own]
        bf16x8 pfrag[4];
        #pragma unroll
        for (int hf = 0; hf < 2; ++hf) {
            const float* pp = hf ? p1 : p0;
            #pragma unroll
            for (int c2 = 0; c2 < 2; ++c2) {
                int rb = c2 * 8;
                unsigned int A0 = pkbf(pp[rb + 1], pp[rb + 0]);
                unsigned int A1 = pkbf(pp[rb + 3], pp[rb + 2]);
                unsigned int B0 = pkbf(pp[rb + 5], pp[rb + 4]);
                unsigned int B1 = pkbf(pp[rb + 7], pp[rb + 6]);
                unsigned int s0 = h ? A0 : B0, s1 = h ? A1 : B1;   // what partner needs
                unsigned int r0 = __shfl_xor(s0, 32), r1 = __shfl_xor(s1, 32);
                u32x4 f;
                f[0] = h ? r0 : A0; f[1] = h ? r1 : A1;
                f[2] = h ? B0 : r0; f[3] = h ? B1 : r1;
                pfrag[hf * 2 + c2] = __builtin_bit_cast(bf16x8, f);
            }
        }

        // rescale accumulator (scalar per lane) then O^T += V^T P^T
        #pragma unroll
        for (int ct = 0; ct < 4; ++ct)
            #pragma unroll
            for (int r = 0; r < 16; ++r) acc[ct][r] *= alpha;
        #pragma unroll
        for (int ct = 0; ct < 4; ++ct) {
            int cr = ct * 32 + il;
            #pragma unroll
            for (int kc2 = 0; kc2 < 4; ++kc2) {
                bf16x8 av = *(const bf16x8*)&vt[cr * 64 + (((kc2 * 2 + h) ^ (cr & 7)) << 3)];
                acc[ct] = __builtin_amdgcn_mfma_f32_32x32x16_bf16(av, pfrag[kc2], acc[ct], 0, 0, 0);
            }
        }
    }

    float inv = __builtin_amdgcn_rcpf(lrow);
    unsigned short* orow = &oT[((size_t)b * NPOS + i0 + w * 32 + il) * NC];
    #pragma unroll
    for (int ct = 0; ct < 4; ++ct)
        #pragma unroll
        for (int r = 0; r < 16; r += 2) {
            int c = ct * 32 + (r & 3) + 8 * (r >> 2) + 4 * h;
            *(unsigned int*)&orow[c] = pkbf(acc[ct][r + 1] * inv, acc[ct][r] * inv);
        }
}

// ---------------- K4: out = wf @ o + bf + x  (grid 64 x 16, 256 thr) ----------------
__global__ __launch_bounds__(256) void proj_kernel(
    const unsigned short* __restrict__ oT, const unsigned short* __restrict__ wfb,
    const float* __restrict__ bf_, const float* __restrict__ x, float* __restrict__ out) {
    const int b = blockIdx.y, i0 = blockIdx.x * 64;
    const int t = threadIdx.x, lane = t & 63, w = t >> 6, quad = lane >> 4, li = lane & 15;
    bf16x8 aw[2][4];
    for (int mt = 0; mt < 2; ++mt)
        for (int kc = 0; kc < 4; ++kc)
            aw[mt][kc] = *(const bf16x8*)&wfb[((w * 2 + mt) * 16 + li) * 128 + kc * 32 + quad * 8];
    for (int nt = 0; nt < 4; ++nt) {
        bf16x8 bo[4];
        for (int kc = 0; kc < 4; ++kc)
            bo[kc] = *(const bf16x8*)&oT[((size_t)b * NPOS + i0 + nt * 16 + li) * NC + kc * 32 + quad * 8];
        for (int mt = 0; mt < 2; ++mt) {
            f32x4 d = {0.f, 0.f, 0.f, 0.f};
            for (int kc = 0; kc < 4; ++kc)
                d = __builtin_amdgcn_mfma_f32_16x16x32_bf16(aw[mt][kc], bo[kc], d, 0, 0, 0);
            int o0 = (w * 2 + mt) * 16 + quad * 4;
            for (int rr = 0; rr < 4; ++rr) {
                size_t idx = ((size_t)(b * NC + o0 + rr)) * NPOS + i0 + nt * 16 + li;
                out[idx] = d[rr] + bf_[o0 + rr] + x[idx];
            }
        }
    }
}

extern "C" void kernel_launch(void* const* d_in, const int* in_sizes, int n_in,
                              void* d_out, int out_size, void* d_ws, size_t ws_size,
                              hipStream_t stream) {
    const float* x   = (const float*)d_in[0];
    const float* gnw = (const float*)d_in[1];
    const float* gnb = (const float*)d_in[2];
    const float* wq  = (const float*)d_in[3];
    const float* bq  = (const float*)d_in[4];
    const float* wk  = (const float*)d_in[5];
    const float* bk  = (const float*)d_in[6];
    const float* wv  = (const float*)d_in[7];
    const float* bv  = (const float*)d_in[8];
    const float* wf  = (const float*)d_in[9];
    const float* bf_ = (const float*)d_in[10];
    float* out = (float*)d_out;

    char* ws = (char*)d_ws;
    float* mean = (float*)(ws + 0);
    float* rstd = (float*)(ws + 512);
    unsigned short* wqb = (unsigned short*)(ws + 1024);
    unsigned short* wkb = wqb + 16384;
    unsigned short* wvb = wkb + 16384;
    unsigned short* wfb = wvb + 16384;
    unsigned short* qT  = (unsigned short*)(ws + 132096);          // [b][n][c] bf16 (SCF-scaled)
    unsigned short* kT  = qT + (size_t)NB * NPOS * NC;             // [b][n][c]
    unsigned short* vv  = kT + (size_t)NB * NPOS * NC;             // [b][c][n]
    unsigned short* oT  = vv + (size_t)NB * NPOS * NC;             // [b][n][c]

    wconv_kernel<<<64, 256, 0, stream>>>(wq, wk, wv, wf, wqb, wkb, wvb, wfb);
    gnstat_kernel<<<128, 256, 0, stream>>>(x, mean, rstd);
    dim3 g(64, 16);
    qkv_kernel<<<g, 256, 0, stream>>>(x, gnw, gnb, mean, rstd, wqb, wkb, wvb, bq, bk, bv, qT, kT, vv);
    dim3 gf(16, 32);
    flash_kernel<<<gf, 256, 0, stream>>>(qT, kT, vv, oT);
    proj_kernel<<<g, 256, 0, stream>>>(oT, wfb, bf_, x, out);
}